// Round 1
// baseline (129.234 us; speedup 1.0000x reference)
//
#include <hip/hip_runtime.h>
#include <math.h>

// ---------------------------------------------------------------------------
// FullyQuantumRNN: 5-qubit recurrent circuit, 32 lanes per batch element
// (one complex amplitude per lane), gates via ds_swizzle xor-pairing.
// CNOT-ring permutations are GF(2)-linear => folded into lane relabeling
// (compile-time masks), costing zero data movement.
// ---------------------------------------------------------------------------

// ---- compile-time permutation algebra ----
constexpr int cnot_ct(int idx, int c, int t, int n) {
    return (idx & (1 << (n - 1 - c))) ? (idx ^ (1 << (n - 1 - t))) : idx;
}
// Composed layer perm P_r: state_new[i] = state_old[P_r(i)]; gates applied w=0..n-1,
// so innermost (first applied to i) is w = n-1.
constexpr int Pfwd_ct(int x, int r, int n) {
    for (int w = n - 1; w >= 0; --w) x = cnot_ct(x, w, (w + r) % n, n);
    return x;
}

// layer-1 lane-pair masks: P1(e_b) for wires 0..4 (e_b = 1 << (4-w))
constexpr int M1W0 = Pfwd_ct(16, 1, 5);  // 24
constexpr int M1W1 = Pfwd_ct(8, 1, 5);   // 12
constexpr int M1W2 = Pfwd_ct(4, 1, 5);   // 6
constexpr int M1W3 = Pfwd_ct(2, 1, 5);   // 3
constexpr int M1W4 = Pfwd_ct(1, 1, 5);   // 25
// final-logical lane-pair masks: P1(P2(1<<bit))
constexpr int FM4 = Pfwd_ct(Pfwd_ct(16, 2, 5), 1, 5);  // 30
constexpr int FM3 = Pfwd_ct(Pfwd_ct(8, 2, 5), 1, 5);   // 15
constexpr int FM2 = Pfwd_ct(Pfwd_ct(4, 2, 5), 1, 5);   // 31
constexpr int FM1 = Pfwd_ct(Pfwd_ct(2, 2, 5), 1, 5);   // 28
constexpr int FM0 = Pfwd_ct(Pfwd_ct(1, 2, 5), 1, 5);   // 14

// runtime inverse perm (per-lane logical index), applied once at kernel start
__device__ __forceinline__ int pinv_rt(int x, int r, int n) {
    #pragma unroll
    for (int w = 0; w < 5; ++w) {
        if (w >= n) break;
        int cbit = 1 << (n - 1 - w), tbit = 1 << (n - 1 - ((w + r) % n));
        if (x & cbit) x ^= tbit;
    }
    return x;
}

template <int MASK>
__device__ __forceinline__ float swz(float x) {
    // BitMode swizzle: src lane = lane ^ MASK (within each 32-lane group)
    return __int_as_float(__builtin_amdgcn_ds_swizzle(__float_as_int(x), (MASK << 10) | 0x1F));
}

// One 1-qubit gate: own amp (sr,si), partner via swizzle; per-lane coefs fold
// the row selection (beta) so both rows use the same FMA shape.
#define GATE(g, MASK) do {                                        \
    float pr_ = swz<(MASK)>(sr), pi_ = swz<(MASK)>(si);           \
    float nr_ = G0[g]*sr - G1[g]*si + G2[g]*pr_ - G3[g]*pi_;      \
    float ni_ = G0[g]*si + G1[g]*sr + G2[g]*pi_ + G3[g]*pr_;      \
    sr = nr_; si = ni_; } while (0)

__global__ __launch_bounds__(256) void qrnn_kernel(
    const float* __restrict__ x_seq, const float* __restrict__ w_rec,
    const float* __restrict__ w_out, float* __restrict__ out, int T, int B) {

    const int tid  = blockIdx.x * blockDim.x + threadIdx.x;
    const int b    = tid >> 5;
    const int lane = tid & 31;
    if (b >= B) return;

    // per-lane logical indices under the relabeling scheme
    const int L1 = pinv_rt(lane, 1, 5);          // logical index during layer-1 gates
    const int M  = pinv_rt(L1, 2, 5);            // final logical index (for expZ)
    const float sign3 = ((M >> 1) & 1) ? -1.f : 1.f;  // wire 3 -> bit 1
    const float sign4 = (M & 1) ? -1.f : 1.f;         // wire 4 -> bit 0

    // ---- precompute per-lane gate coefficients from w_rec (batch-invariant) ----
    float G0[10], G1[10], G2[10], G3[10];
    #pragma unroll
    for (int l = 0; l < 2; ++l) {
        #pragma unroll
        for (int w = 0; w < 5; ++w) {
            const int g = l * 5 + w;
            const float phi = w_rec[l * 15 + w * 3 + 0];
            const float the = w_rec[l * 15 + w * 3 + 1];
            const float ome = w_rec[l * 15 + w * 3 + 2];
            const float cs = cosf(0.5f * the), ss = sinf(0.5f * the);
            const float cp = cosf(0.5f * (phi + ome)), sp = sinf(0.5f * (phi + ome));
            const float cm = cosf(0.5f * (phi - ome)), sm = sinf(0.5f * (phi - ome));
            // m = [[a, -b], [conj(b), conj(a)]], a = e^{-i(phi+ome)/2} c, b = e^{+i(phi-ome)/2} s
            const float are = cp * cs, aim = -sp * cs;
            const float bre = cm * ss, bim = sm * ss;
            const int logical = (l == 0) ? lane : L1;
            const int beta = (logical >> (4 - w)) & 1;
            G0[g] = are;
            G1[g] = beta ? -aim : aim;
            G2[g] = beta ? bre : -bre;
            G3[g] = -bim;
        }
    }

    const int b0i = (lane >> 4) & 1, b1i = (lane >> 3) & 1, b2i = (lane >> 2) & 1,
              b3i = (lane >> 1) & 1, b4i = lane & 1;

    float h0 = 0.f, h1 = 0.f;

    #pragma unroll 1
    for (int t = 0; t < T; ++t) {
        const float* xp = x_seq + ((size_t)t * B + b) * 3;
        float c0, s0, c1, s1, c2, s2, c3, s3, c4, s4;
        __sincosf(0.5f * xp[0], &s0, &c0);
        __sincosf(0.5f * xp[1], &s1, &c1);
        __sincosf(0.5f * xp[2], &s2, &c2);
        __sincosf(0.5f * h0, &s3, &c3);
        __sincosf(0.5f * h1, &s4, &c4);
        // product state: amp(idx) = prod_w (bit_w ? sin : cos), purely real
        float sr = (b0i ? s0 : c0) * (b1i ? s1 : c1) * (b2i ? s2 : c2) *
                   (b3i ? s3 : c3) * (b4i ? s4 : c4);
        float si = 0.f;

        // entangle layer 0 (logical == lane): masks e_b
        GATE(0, 16); GATE(1, 8); GATE(2, 4); GATE(3, 2); GATE(4, 1);
        // [CNOT ring r=1: pure relabeling, no data movement]
        // entangle layer 1: masks P1(e_b)
        GATE(5, M1W0); GATE(6, M1W1); GATE(7, M1W2); GATE(8, M1W3); GATE(9, M1W4);
        // [CNOT ring r=2: relabeling again]

        // expZ on wires 3 (bit1 of final logical) and 4 (bit0)
        float p = sr * sr + si * si;
        p += swz<FM4>(p); p += swz<FM3>(p); p += swz<FM2>(p);
        float q0 = sign3 * p; q0 += swz<FM1>(q0); q0 += swz<FM0>(q0);
        float q1 = sign4 * p; q1 += swz<FM1>(q1); q1 += swz<FM0>(q1);
        h0 = q0; h1 = q1;   // broadcast in all 32 lanes by the butterfly
    }

    // ---- readout: 2-qubit circuit, computed redundantly per lane ----
    float ch0, sh0, ch1, sh1;
    __sincosf(0.5f * h0, &sh0, &ch0);
    __sincosf(0.5f * h1, &sh1, &ch1);
    float vr0 = ch0 * ch1, vr1 = ch0 * sh1, vr2 = sh0 * ch1, vr3 = sh0 * sh1;
    float vi0 = 0.f, vi1 = 0.f, vi2 = 0.f, vi3 = 0.f;

    #pragma unroll
    for (int l = 0; l < 2; ++l) {
        #pragma unroll
        for (int w = 0; w < 2; ++w) {
            const float phi = w_out[l * 6 + w * 3 + 0];
            const float the = w_out[l * 6 + w * 3 + 1];
            const float ome = w_out[l * 6 + w * 3 + 2];
            const float cs = cosf(0.5f * the), ss = sinf(0.5f * the);
            const float cp = cosf(0.5f * (phi + ome)), sp = sinf(0.5f * (phi + ome));
            const float cm = cosf(0.5f * (phi - ome)), sm = sinf(0.5f * (phi - ome));
            const float are = cp * cs, aim = -sp * cs;
            const float bre = cm * ss, bim = sm * ss;
            // apply to pair (v0, v1): n0 = a*v0 - b*v1 ; n1 = conj(b)*v0 + conj(a)*v1
            #define AP2(r0, i0, r1, i1) do {                                  \
                float n0r = are*(r0) - aim*(i0) - bre*(r1) + bim*(i1);        \
                float n0i = are*(i0) + aim*(r0) - bre*(i1) - bim*(r1);        \
                float n1r = bre*(r0) + bim*(i0) + are*(r1) + aim*(i1);        \
                float n1i = bre*(i0) - bim*(r0) + are*(i1) - aim*(r1);        \
                r0 = n0r; i0 = n0i; r1 = n1r; i1 = n1i; } while (0)
            if (w == 0) { AP2(vr0, vi0, vr2, vi2); AP2(vr1, vi1, vr3, vi3); }
            else        { AP2(vr0, vi0, vr1, vi1); AP2(vr2, vi2, vr3, vi3); }
            #undef AP2
        }
        // CNOT(0,1) then CNOT(1,0): composed perm P = [0,2,3,1]; new[i] = old[P[i]]
        float tr1 = vr2, ti1 = vi2, tr2 = vr3, ti2 = vi3, tr3 = vr1, ti3 = vi1;
        vr1 = tr1; vi1 = ti1; vr2 = tr2; vi2 = ti2; vr3 = tr3; vi3 = ti3;
    }

    const float outv = (vr0 * vr0 + vi0 * vi0 + vr1 * vr1 + vi1 * vi1) -
                       (vr2 * vr2 + vi2 * vi2 + vr3 * vr3 + vi3 * vi3);
    if (lane == 0) out[b] = outv;
}

extern "C" void kernel_launch(void* const* d_in, const int* in_sizes, int n_in,
                              void* d_out, int out_size, void* d_ws, size_t ws_size,
                              hipStream_t stream) {
    const float* x_seq = (const float*)d_in[0];
    const float* w_rec = (const float*)d_in[1];
    const float* w_out = (const float*)d_in[2];
    float* out = (float*)d_out;

    const int B = out_size;                 // 8192
    const int T = in_sizes[0] / (B * 3);    // 32

    const int threads = B * 32;
    const int block = 256;
    const int grid = (threads + block - 1) / block;
    hipLaunchKernelGGL(qrnn_kernel, dim3(grid), dim3(block), 0, stream,
                       x_seq, w_rec, w_out, out, T, B);
}

// Round 2
// 94.421 us; speedup vs baseline: 1.3687x; 1.3687x over previous
//
#include <hip/hip_runtime.h>
#include <math.h>

// ---------------------------------------------------------------------------
// FullyQuantumRNN, round 2: 8 lanes/batch x 4 amps/lane (reg bits = amp bits
// 3,4). CNOT rings folded into index relabeling (R1-verified). New: a GF(2)
// lane relabel A makes 6/7 cross gates + 3/4 reduction stages DPP (quad_perm /
// row_half_mirror) instead of ds_swizzle; only 2 LDS rounds per step remain.
// All masks/functionals constexpr-derived and static_assert-checked.
// ---------------------------------------------------------------------------

// ---- compile-time permutation algebra ----
constexpr int cnot_ct(int idx, int c, int t) {
    return (idx & (1 << (4 - c))) ? (idx ^ (1 << (4 - t))) : idx;
}
constexpr int Pfwd_ct(int x, int r) {            // layer perm: state_new[i]=state_old[P(i)]
    for (int w = 4; w >= 0; --w) x = cnot_ct(x, w, (w + r) % 5);
    return x;
}
constexpr int Pinv_ct(int x, int r) {
    for (int w = 0; w <= 4; ++w) x = cnot_ct(x, w, (w + r) % 5);
    return x;
}
static_assert(Pinv_ct(Pfwd_ct(13, 1), 1) == 13, "inv1");
static_assert(Pinv_ct(Pfwd_ct(22, 2), 2) == 22, "inv2");

// gate pair masks (amp-index xor) for gates g=0..9 (layer0 w0..w4, layer1 w0..w4)
constexpr int GMASK[10] = {16, 8, 4, 2, 1,
                           Pfwd_ct(16,1), Pfwd_ct(8,1), Pfwd_ct(4,1), Pfwd_ct(2,1), Pfwd_ct(1,1)};
// beta (row-select) functionals as xor-masks over amp index i
constexpr int fmask_l1(int pb) {
    int f = 0;
    for (int b = 0; b < 5; ++b) if ((Pinv_ct(1 << b, 1) >> pb) & 1) f |= 1 << b;
    return f;
}
constexpr int FMASK[10] = {16, 8, 4, 2, 1,
                           fmask_l1(4), fmask_l1(3), fmask_l1(2), fmask_l1(1), fmask_l1(0)};
// final-logical functionals for expZ signs (wire3 -> bit1, wire4 -> bit0)
constexpr int cinv_ct(int x) { return Pinv_ct(Pinv_ct(x, 1), 2); }
constexpr int fmask_fin(int pb) {
    int f = 0;
    for (int b = 0; b < 5; ++b) if ((cinv_ct(1 << b) >> pb) & 1) f |= 1 << b;
    return f;
}
constexpr int SF3 = fmask_fin(1);
constexpr int SF4 = fmask_fin(0);
constexpr int FMf(int b) { return Pfwd_ct(Pfwd_ct(1 << b, 2), 1); }   // P1(P2(e_b))

// p-reduction subgroup = span{FMf(4),FMf(3),FMf(2)}; we use generators {16,1,14}
constexpr unsigned span3_ct(int a, int b, int c) {
    unsigned m = 0;
    for (int i = 0; i < 8; ++i) {
        int v = ((i & 1) ? a : 0) ^ ((i & 2) ? b : 0) ^ ((i & 4) ? c : 0);
        m |= 1u << v;
    }
    return m;
}
constexpr unsigned PSPAN = span3_ct(FMf(4), FMf(3), FMf(2));
static_assert(PSPAN == span3_ct(16, 1, 14), "p-stage generators span mismatch");
constexpr bool pspan_ok() {
    int regs = 0;
    for (int v = 0; v < 32; ++v) if ((PSPAN >> v) & 1) {
        if (__builtin_popcount(v & SF3) & 1) return false;   // sign3 coset-constant
        if (__builtin_popcount(v & SF4) & 1) return false;   // sign4 coset-constant
        regs |= 1 << ((v >> 3) & 3);                         // reg projections
    }
    return regs == 0xF;                                      // reg-uniform after p-reduce
}
static_assert(pspan_ok(), "p-subgroup sign/reg structure");
static_assert((SF3 & 24) == 0, "SF3 lane-only");

// ---- physical lane relabel A (maximizes DPP-able xor masks) ----
constexpr int A_map(int l)   { return ((l&1)?7:0) ^ ((l&2)?1:0) ^ ((l&4)?2:0); }
constexpr int Ainv_map(int l){ return ((l&1)?2:0) ^ ((l&2)?4:0) ^ ((l&4)?7:0); }
constexpr bool a_ok() { for (int i = 0; i < 8; ++i) if (A_map(Ainv_map(i)) != i) return false; return true; }
static_assert(a_ok(), "A inverse");

// ---- cross-lane move: identity / DPP / ds_swizzle, chosen by xor value ----
template<int CTRL> __device__ __forceinline__ float dppf(float x) {
    return __int_as_float(__builtin_amdgcn_mov_dpp(__float_as_int(x), CTRL, 0xF, 0xF, true));
}
template<int PL> __device__ __forceinline__ float mvf(float x) {
    if constexpr (PL == 0) return x;
    else if constexpr (PL == 1) return dppf<0xB1>(x);    // quad_perm [1,0,3,2] = xor1
    else if constexpr (PL == 2) return dppf<0x4E>(x);    // quad_perm [2,3,0,1] = xor2
    else if constexpr (PL == 3) return dppf<0x1B>(x);    // quad_perm [3,2,1,0] = xor3
    else if constexpr (PL == 7) return dppf<0x141>(x);   // row_half_mirror = xor7
    else return __int_as_float(__builtin_amdgcn_ds_swizzle(__float_as_int(x), (PL << 10) | 0x1F));
}

// ---- one gate: 4 amps/lane, partner via reg-index xor + lane move ----
template<int g>
__device__ __forceinline__ void gate(float (&vr)[4], float (&vi)[4],
                                     const float (&G0)[10], const float (&G1)[10],
                                     const float (&G2)[10], const float (&G3)[10]) {
    constexpr int m  = GMASK[g];
    constexpr int rm = (((m >> 4) & 1) << 1) | ((m >> 3) & 1);  // reg-index xor
    constexpr int pl = A_map(m & 7);                            // physical lane xor
    float nr[4], ni[4];
    #pragma unroll
    for (int r = 0; r < 4; ++r) {
        const float pr = mvf<pl>(vr[r ^ rm]);
        const float pi = mvf<pl>(vi[r ^ rm]);
        const int  rb = ((r >> 1) << 4) | ((r & 1) << 3);       // amp bits of slot r
        const bool sg = __builtin_popcount(rb & FMASK[g]) & 1;  // compile-time after unroll
        const float g1 = sg ? -G1[g] : G1[g];
        const float g2 = sg ? -G2[g] : G2[g];
        nr[r] = G0[g]*vr[r] - g1*vi[r] + g2*pr - G3[g]*pi;
        ni[r] = G0[g]*vi[r] + g1*vr[r] + g2*pi + G3[g]*pr;
    }
    #pragma unroll
    for (int r = 0; r < 4; ++r) { vr[r] = nr[r]; vi[r] = ni[r]; }
}

__device__ __forceinline__ void fsc(float a, float& s, float& c) {
    const float r = a * 0.15915494309189535f;   // /(2*pi): v_sin/v_cos take revolutions
    s = __builtin_amdgcn_sinf(r);
    c = __builtin_amdgcn_cosf(r);
}

__global__ __launch_bounds__(256, 1) void qrnn_kernel(
    const float* __restrict__ x_seq, const float* __restrict__ w_rec,
    const float* __restrict__ w_out, float* __restrict__ out, int T, int B) {

    const int tid = blockIdx.x * blockDim.x + threadIdx.x;
    const int b   = tid >> 3;
    if (b >= B) return;
    const int lam = tid & 7;            // physical lane-part
    const int l   = Ainv_map(lam);      // logical amp bits (i2,i1,i0)

    // ---- per-lane gate coefficients (lane part of beta folded in) ----
    float G0[10], G1[10], G2[10], G3[10];
    #pragma unroll
    for (int g = 0; g < 10; ++g) {
        const int li = g / 5, w = g % 5;
        const float phi = w_rec[li*15 + w*3 + 0];
        const float the = w_rec[li*15 + w*3 + 1];
        const float ome = w_rec[li*15 + w*3 + 2];
        float ss, cs, sp, cp, sm, cm;
        fsc(0.5f*the, ss, cs);
        fsc(0.5f*(phi+ome), sp, cp);
        fsc(0.5f*(phi-ome), sm, cm);
        const float are = cp*cs, aim = -sp*cs;
        const float bre = cm*ss, bim = sm*ss;
        const bool bl = __builtin_popcount(l & FMASK[g]) & 1;   // lane part of beta
        G0[g] = are;
        G1[g] = bl ? -aim : aim;
        G2[g] = bl ? bre : -bre;
        G3[g] = -bim;
    }
    const float s3f = (__builtin_popcount(l & (SF3 & 7)) & 1) ? -1.f : 1.f;
    const float s4f = (__builtin_popcount(l & (SF4 & 7)) & 1) ? -1.f : 1.f;
    const bool l2 = l & 4, l1b = l & 2, l0b = l & 1;

    const float* xp0 = x_seq + (size_t)b * 3;
    float nx0 = xp0[0], nx1 = xp0[1], nx2 = xp0[2];
    float h0 = 0.f, h1 = 0.f;

    #pragma unroll 1
    for (int t = 0; t < T; ++t) {
        const float x0 = nx0, x1 = nx1, x2 = nx2;
        const int tn = (t + 1 < T) ? t + 1 : t;            // prefetch next step's x
        const float* xn = x_seq + ((size_t)tn * B + b) * 3;
        nx0 = xn[0]; nx1 = xn[1]; nx2 = xn[2];

        float s0,c0,s1,c1,s2,c2,s3,c3,s4,c4;
        fsc(0.5f*x0, s0, c0); fsc(0.5f*x1, s1, c1); fsc(0.5f*x2, s2, c2);
        fsc(0.5f*h0, s3, c3); fsc(0.5f*h1, s4, c4);

        // product state: reg slots = (wire0,wire1), lane = (wire2,wire3,wire4)
        const float Xl = (l2 ? s2 : c2) * (l1b ? s3 : c3) * (l0b ? s4 : c4);
        float vr[4], vi[4];
        vr[0] = c0*c1*Xl; vr[1] = c0*s1*Xl; vr[2] = s0*c1*Xl; vr[3] = s0*s1*Xl;
        vi[0] = 0.f; vi[1] = 0.f; vi[2] = 0.f; vi[3] = 0.f;

        gate<0>(vr,vi,G0,G1,G2,G3); gate<1>(vr,vi,G0,G1,G2,G3);
        gate<2>(vr,vi,G0,G1,G2,G3); gate<3>(vr,vi,G0,G1,G2,G3);
        gate<4>(vr,vi,G0,G1,G2,G3);
        gate<5>(vr,vi,G0,G1,G2,G3); gate<6>(vr,vi,G0,G1,G2,G3);
        gate<7>(vr,vi,G0,G1,G2,G3); gate<8>(vr,vi,G0,G1,G2,G3);
        gate<9>(vr,vi,G0,G1,G2,G3);

        // expZ: p-reduce over span{16,1,14} (== span{FM4,FM3,FM2}, asserted)
        const float p0 = vr[0]*vr[0] + vi[0]*vi[0];
        const float p1 = vr[1]*vr[1] + vi[1]*vi[1];
        const float p2 = vr[2]*vr[2] + vi[2]*vi[2];
        const float p3 = vr[3]*vr[3] + vi[3]*vi[3];
        float sA = p0 + p2;                         // mask16: sum over i4 (reg)
        float sB = p1 + p3;
        sA += mvf<A_map(1)>(sA);                    // mask1: lane, DPP xor7
        sB += mvf<A_map(1)>(sB);
        const float tsum = sA + mvf<A_map(14 & 7)>(sB);   // mask14: lane xor + reg flip
        float q0 = s3f * tsum, q1 = s4f * tsum;
        constexpr int QA = A_map(FMf(1) & 7);       // = 5 -> ds_swizzle
        constexpr int QB = A_map(FMf(0) & 7);       // = 3 -> quad_perm
        q0 += mvf<QA>(q0); q1 += mvf<QA>(q1);
        q0 += mvf<QB>(q0); q1 += mvf<QB>(q1);
        h0 = q0; h1 = q1;                           // identical in all 8 lanes
    }

    // ---- readout: 2-qubit circuit (verified in R1), redundant per lane ----
    float ch0, sh0, ch1, sh1;
    fsc(0.5f*h0, sh0, ch0);
    fsc(0.5f*h1, sh1, ch1);
    float vr0 = ch0*ch1, vr1 = ch0*sh1, vr2 = sh0*ch1, vr3 = sh0*sh1;
    float vi0 = 0.f, vi1 = 0.f, vi2 = 0.f, vi3 = 0.f;

    #pragma unroll
    for (int li = 0; li < 2; ++li) {
        #pragma unroll
        for (int w = 0; w < 2; ++w) {
            const float phi = w_out[li*6 + w*3 + 0];
            const float the = w_out[li*6 + w*3 + 1];
            const float ome = w_out[li*6 + w*3 + 2];
            float ss, cs, sp, cp, sm, cm;
            fsc(0.5f*the, ss, cs);
            fsc(0.5f*(phi+ome), sp, cp);
            fsc(0.5f*(phi-ome), sm, cm);
            const float are = cp*cs, aim = -sp*cs;
            const float bre = cm*ss, bim = sm*ss;
            #define AP2(r0, i0, r1, i1) do {                                  \
                float n0r = are*(r0) - aim*(i0) - bre*(r1) + bim*(i1);        \
                float n0i = are*(i0) + aim*(r0) - bre*(i1) - bim*(r1);        \
                float n1r = bre*(r0) + bim*(i0) + are*(r1) + aim*(i1);        \
                float n1i = bre*(i0) - bim*(r0) + are*(i1) - aim*(r1);        \
                r0 = n0r; i0 = n0i; r1 = n1r; i1 = n1i; } while (0)
            if (w == 0) { AP2(vr0, vi0, vr2, vi2); AP2(vr1, vi1, vr3, vi3); }
            else        { AP2(vr0, vi0, vr1, vi1); AP2(vr2, vi2, vr3, vi3); }
            #undef AP2
        }
        // CNOT(0,1) then CNOT(1,0): composed perm [0,2,3,1]
        float tr1 = vr2, ti1 = vi2, tr2 = vr3, ti2 = vi3, tr3 = vr1, ti3 = vi1;
        vr1 = tr1; vi1 = ti1; vr2 = tr2; vi2 = ti2; vr3 = tr3; vi3 = ti3;
    }

    const float outv = (vr0*vr0 + vi0*vi0 + vr1*vr1 + vi1*vi1) -
                       (vr2*vr2 + vi2*vi2 + vr3*vr3 + vi3*vi3);
    if ((tid & 7) == 0) out[b] = outv;
}

extern "C" void kernel_launch(void* const* d_in, const int* in_sizes, int n_in,
                              void* d_out, int out_size, void* d_ws, size_t ws_size,
                              hipStream_t stream) {
    const float* x_seq = (const float*)d_in[0];
    const float* w_rec = (const float*)d_in[1];
    const float* w_out = (const float*)d_in[2];
    float* out = (float*)d_out;

    const int B = out_size;                 // 8192
    const int T = in_sizes[0] / (B * 3);    // 32

    const long long threads = (long long)B * 8;
    const int block = 256;
    const int grid = (int)((threads + block - 1) / block);
    hipLaunchKernelGGL(qrnn_kernel, dim3(grid), dim3(block), 0, stream,
                       x_seq, w_rec, w_out, out, T, B);
}

// Round 4
// 89.416 us; speedup vs baseline: 1.4453x; 1.0560x over previous
//
#include <hip/hip_runtime.h>
#include <math.h>

// ---------------------------------------------------------------------------
// FullyQuantumRNN, round 4: 16 lanes/batch x 2 amps/lane (reg bit = amp bit4).
// Rot = Rz(omega)Ry(theta)Rz(phi); diagonals commute across wires, so each
// layer = D_omega * (prod Ry) * D_phi. D_phi0 folds into init, D_omega0+D_phi1
// merge into precomputed per-(lane,slot) diagonal E1, final D_omega1 dropped
// (|amp|^2 phase-blind). All cross-lane via DPP (zero LDS). R3 fix: q-stage
// masks only need independence mod the lane-duplication subgroup; use coset
// reps {12,8} (single-DPP under A4), asserted equivalent to FMf mod PSPAN.
// ---------------------------------------------------------------------------

// ---- compile-time permutation algebra (R1/R2-verified) ----
constexpr int cnot_ct(int idx, int c, int t) {
    return (idx & (1 << (4 - c))) ? (idx ^ (1 << (4 - t))) : idx;
}
constexpr int Pfwd_ct(int x, int r) {            // layer perm: new[i]=old[P(i)]
    for (int w = 4; w >= 0; --w) x = cnot_ct(x, w, (w + r) % 5);
    return x;
}
constexpr int Pinv_ct(int x, int r) {
    for (int w = 0; w <= 4; ++w) x = cnot_ct(x, w, (w + r) % 5);
    return x;
}
static_assert(Pinv_ct(Pfwd_ct(13, 1), 1) == 13, "inv1");
static_assert(Pinv_ct(Pfwd_ct(22, 2), 2) == 22, "inv2");

constexpr int GMASK[10] = {16, 8, 4, 2, 1,
                           Pfwd_ct(16,1), Pfwd_ct(8,1), Pfwd_ct(4,1), Pfwd_ct(2,1), Pfwd_ct(1,1)};
constexpr int fmask_l1(int pb) {
    int f = 0;
    for (int b = 0; b < 5; ++b) if ((Pinv_ct(1 << b, 1) >> pb) & 1) f |= 1 << b;
    return f;
}
constexpr int FMASK[10] = {16, 8, 4, 2, 1,
                           fmask_l1(4), fmask_l1(3), fmask_l1(2), fmask_l1(1), fmask_l1(0)};
constexpr int cinv_ct(int x) { return Pinv_ct(Pinv_ct(x, 1), 2); }
constexpr int fmask_fin(int pb) {
    int f = 0;
    for (int b = 0; b < 5; ++b) if ((cinv_ct(1 << b) >> pb) & 1) f |= 1 << b;
    return f;
}
constexpr int SF3 = fmask_fin(1);
constexpr int SF4 = fmask_fin(0);
constexpr int FMf(int b) { return Pfwd_ct(Pfwd_ct(1 << b, 2), 1); }

// p-reduction subgroup span{FMf(4),FMf(3),FMf(2)} must equal span{16,1,14}
constexpr unsigned span3_ct(int a, int b, int c) {
    unsigned m = 0;
    for (int i = 0; i < 8; ++i) {
        int v = ((i & 1) ? a : 0) ^ ((i & 2) ? b : 0) ^ ((i & 4) ? c : 0);
        m |= 1u << v;
    }
    return m;
}
constexpr unsigned PSPAN = span3_ct(FMf(4), FMf(3), FMf(2));
static_assert(PSPAN == span3_ct(16, 1, 14), "p-stage basis {16,1,14} spans PSPAN");
static_assert((PSPAN >> 16) & 1, "16 in PSPAN: reg dim collapsed by p-reduce");
constexpr bool in_pspan(int v) { return (PSPAN >> (v & 31)) & 1; }
constexpr bool pspan_ok() {                      // signs constant on p-cosets
    for (int v = 0; v < 32; ++v) if ((PSPAN >> v) & 1) {
        if (__builtin_popcount(v & SF3) & 1) return false;
        if (__builtin_popcount(v & SF4) & 1) return false;
    }
    return true;
}
static_assert(pspan_ok(), "sign functionals vanish on PSPAN");
static_assert((SF3 & 16) == 0 && (SF4 & 16) == 0, "signs lane-only");

// q-stage lane-mask coset reps (mod PSPAN) for FMf(1), FMf(0).
// Correctness needs: (a) rep ~ FMf mod PSPAN, (b) reps lane-only, (c)
// {QM1, QM0, QM1^QM0} all outside the lane-duplication subgroup PSPAN∩lanes
// so the butterfly covers the 4-coset quotient exactly once per coset.
constexpr int QM1 = 12;
constexpr int QM0 = 8;
static_assert((QM1 & 16) == 0 && (QM0 & 16) == 0, "q reps lane-only");
static_assert(in_pspan(QM1 ^ FMf(1)), "QM1 ~ FMf(1) mod PSPAN");
static_assert(in_pspan(QM0 ^ FMf(0)), "QM0 ~ FMf(0) mod PSPAN");
static_assert(!in_pspan(QM1) && !in_pspan(QM0) && !in_pspan(QM1 ^ QM0),
              "q reps independent mod duplication subgroup");

// ---- physical lane relabel A (4-bit GF(2) linear, maximizes single-DPP) ----
constexpr int A4(int l) {
    return ((l & 1) ? 7 : 0) ^ ((l & 2) ? 2 : 0) ^ ((l & 4) ? 12 : 0) ^ ((l & 8) ? 15 : 0);
}
constexpr int Ainv4(int p) {
    for (int l = 0; l < 16; ++l) if (A4(l) == p) return l;
    return -1;
}
constexpr bool a_bij() {
    for (int p = 0; p < 16; ++p) { int l = Ainv4(p); if (l < 0 || A4(l) != p) return false; }
    for (int p = 0; p < 16; ++p) {
        int lin = ((p&1)?Ainv4(1):0) ^ ((p&2)?Ainv4(2):0) ^ ((p&4)?Ainv4(4):0) ^ ((p&8)?Ainv4(8):0);
        if (lin != Ainv4(p)) return false;
    }
    return true;
}
static_assert(a_bij(), "A bijective, inverse linear");

__device__ __forceinline__ int ainv_rt(int p) {
    return ((p & 1) ? Ainv4(1) : 0) ^ ((p & 2) ? Ainv4(2) : 0) ^
           ((p & 4) ? Ainv4(4) : 0) ^ ((p & 8) ? Ainv4(8) : 0);
}

// runtime Pinv (for E1 phase precompute)
__device__ __forceinline__ int pinv_rt(int x, int r) {
    #pragma unroll
    for (int w = 0; w < 5; ++w) {
        int cbit = 1 << (4 - w), tbit = 1 << (4 - ((w + r) % 5));
        if (x & cbit) x ^= tbit;
    }
    return x;
}

// ---- cross-lane xor move: pure DPP (composed when needed), zero LDS ----
template<int CTRL> __device__ __forceinline__ float dppf(float x) {
    return __int_as_float(__builtin_amdgcn_mov_dpp(__float_as_int(x), CTRL, 0xF, 0xF, true));
}
template<int PL> __device__ __forceinline__ float mvf(float x) {
    if constexpr (PL == 0)  return x;
    else if constexpr (PL == 1)  return dppf<0xB1>(x);    // quad_perm xor1
    else if constexpr (PL == 2)  return dppf<0x4E>(x);    // quad_perm xor2
    else if constexpr (PL == 3)  return dppf<0x1B>(x);    // quad_perm xor3
    else if constexpr (PL == 7)  return dppf<0x141>(x);   // row_half_mirror = xor7
    else if constexpr (PL == 15) return dppf<0x140>(x);   // row_mirror = xor15
    else if constexpr (PL & 8)   return mvf<PL ^ 15>(dppf<0x140>(x));
    else                         return mvf<PL ^ 7>(dppf<0x141>(x));
}

// ---- one Ry gate on 2 slots: new(s) = c*v(s) + (2*beta(s)-1)*s_theta*v(s^m)
template<int g>
__device__ __forceinline__ void ry_gate(float (&vr)[2], float (&vi)[2],
                                        const float (&Cg)[10], const float (&Sg)[10]) {
    constexpr int m  = GMASK[g];
    constexpr int rm = (m >> 4) & 1;          // slot xor
    constexpr int pl = A4(m & 15);            // physical lane xor
    constexpr int fb = (FMASK[g] >> 4) & 1;   // slot part of row functional
    const float pr0 = mvf<pl>(vr[rm]),     pi0 = mvf<pl>(vi[rm]);
    const float pr1 = mvf<pl>(vr[1 ^ rm]), pi1 = mvf<pl>(vi[1 ^ rm]);
    const float t0r = Sg[g] * pr0, t0i = Sg[g] * pi0;
    const float t1r = Sg[g] * pr1, t1i = Sg[g] * pi1;
    vr[0] = fmaf(Cg[g], vr[0], t0r);
    vi[0] = fmaf(Cg[g], vi[0], t0i);
    if constexpr (fb) { vr[1] = fmaf(Cg[g], vr[1], -t1r); vi[1] = fmaf(Cg[g], vi[1], -t1i); }
    else              { vr[1] = fmaf(Cg[g], vr[1],  t1r); vi[1] = fmaf(Cg[g], vi[1],  t1i); }
}

__global__ __launch_bounds__(256, 2) void qrnn_kernel(
    const float* __restrict__ x_seq, const float* __restrict__ w_rec,
    const float* __restrict__ w_out, float* __restrict__ out, int T, int B) {

    const int tid = blockIdx.x * blockDim.x + threadIdx.x;
    const int b   = tid >> 4;
    if (b >= B) return;
    const int lam = tid & 15;           // physical lane part
    const int l   = ainv_rt(lam);       // logical amp bits 3..0 (wires 1..4)

    // ---- precompute (libm precision, hoisted): Ry coefs + merged diagonals ----
    float Cg[10], Sg[10];
    #pragma unroll
    for (int g = 0; g < 10; ++g) {
        const float the = w_rec[(g / 5) * 15 + (g % 5) * 3 + 1];
        const float c = cosf(0.5f * the), s = sinf(0.5f * the);
        const bool bl = __popc(l & (FMASK[g] & 15)) & 1;
        Cg[g] = c;
        Sg[g] = bl ? s : -s;            // (2*beta_lane-1)*s
    }
    float P0r[2], P0i[2], E1r[2], E1i[2];
    #pragma unroll
    for (int r = 0; r < 2; ++r) {
        const int s_idx = (r << 4) | l;         // storage index (layer-0 frame)
        const int j     = pinv_rt(s_idx, 1);    // layer-1 frame index
        float a0 = 0.f, e1 = 0.f;
        #pragma unroll
        for (int w = 0; w < 5; ++w) {
            const float sg0 = ((s_idx >> (4 - w)) & 1) ? 0.5f : -0.5f;
            const float sg1 = ((j     >> (4 - w)) & 1) ? 0.5f : -0.5f;
            a0 += sg0 * w_rec[w * 3 + 0];              // phi, layer 0
            e1 += sg0 * w_rec[w * 3 + 2];              // omega, layer 0
            e1 += sg1 * w_rec[15 + w * 3 + 0];         // phi, layer 1
        }
        P0r[r] = cosf(a0); P0i[r] = sinf(a0);
        E1r[r] = cosf(e1); E1i[r] = sinf(e1);
    }
    const float s3f = (__popc(l & SF3) & 1) ? -1.f : 1.f;
    const float s4f = (__popc(l & SF4) & 1) ? -1.f : 1.f;
    // sin-as-cos offsets (quarter revolutions) for the 4 lane-bit wires
    const float o1 = (l & 8) ? 0.25f : 0.f;   // wire1 (x1)
    const float o2 = (l & 4) ? 0.25f : 0.f;   // wire2 (x2)
    const float o3 = (l & 2) ? 0.25f : 0.f;   // wire3 (h0)
    const float o4 = (l & 1) ? 0.25f : 0.f;   // wire4 (h1)
    constexpr float K = 0.5f * 0.15915494309189535f;   // 0.5/(2*pi): rad->rev

    const float* xp0 = x_seq + (size_t)b * 3;
    float nx0 = xp0[0], nx1 = xp0[1], nx2 = xp0[2];
    float h0 = 0.f, h1 = 0.f;

    #pragma unroll 1
    for (int t = 0; t < T; ++t) {
        const float x0 = nx0, x1 = nx1, x2 = nx2;
        const int tn = (t + 1 < T) ? t + 1 : t;
        const float* xn = x_seq + ((size_t)tn * B + b) * 3;
        nx0 = xn[0]; nx1 = xn[1]; nx2 = xn[2];

        // product state (real), lane picks sin-or-cos via quarter-rev offset
        const float c0 = __builtin_amdgcn_cosf(x0 * K);
        const float s0 = __builtin_amdgcn_cosf(fmaf(x0, K, -0.25f));
        const float f1 = __builtin_amdgcn_cosf(fmaf(x1, K, -o1));
        const float f2 = __builtin_amdgcn_cosf(fmaf(x2, K, -o2));
        const float f3 = __builtin_amdgcn_cosf(fmaf(h0, K, -o3));
        const float f4 = __builtin_amdgcn_cosf(fmaf(h1, K, -o4));
        const float Xl = f1 * f2 * f3 * f4;
        const float b0v = c0 * Xl, b1v = s0 * Xl;
        // init with D_phi0 phase folded in
        float vr[2] = { b0v * P0r[0], b1v * P0r[1] };
        float vi[2] = { b0v * P0i[0], b1v * P0i[1] };

        // layer 0 Ry's
        ry_gate<0>(vr, vi, Cg, Sg); ry_gate<1>(vr, vi, Cg, Sg);
        ry_gate<2>(vr, vi, Cg, Sg); ry_gate<3>(vr, vi, Cg, Sg);
        ry_gate<4>(vr, vi, Cg, Sg);
        // merged diagonal E1 = D_omega0 * (P1-frame D_phi1)
        #pragma unroll
        for (int r = 0; r < 2; ++r) {
            const float nr = vr[r] * E1r[r] - vi[r] * E1i[r];
            const float ni = vr[r] * E1i[r] + vi[r] * E1r[r];
            vr[r] = nr; vi[r] = ni;
        }
        // layer 1 Ry's (D_omega1 dropped: phase-blind measurement)
        ry_gate<5>(vr, vi, Cg, Sg); ry_gate<6>(vr, vi, Cg, Sg);
        ry_gate<7>(vr, vi, Cg, Sg); ry_gate<8>(vr, vi, Cg, Sg);
        ry_gate<9>(vr, vi, Cg, Sg);

        // expZ reduce: p-stages over span{16,1,14}, then signed q-stages
        const float p0 = fmaf(vr[0], vr[0], vi[0] * vi[0]);
        const float p1 = fmaf(vr[1], vr[1], vi[1] * vi[1]);
        float tq = p0 + p1;                 // mask16 (reg)
        tq += mvf<A4(1)>(tq);               // mask1  -> phys xor7 (half_mirror)
        tq += mvf<A4(14)>(tq);              // mask14 -> phys xor1 (quad_perm)
        float q0 = s3f * tq, q1 = s4f * tq;
        q0 += mvf<A4(QM1)>(q0);             // QM1=12 -> phys xor3 (quad_perm)
        q1 += mvf<A4(QM1)>(q1);
        q0 += mvf<A4(QM0)>(q0);             // QM0=8 -> phys xor15 (row_mirror)
        q1 += mvf<A4(QM0)>(q1);
        h0 = q0; h1 = q1;                   // uniform across all 16 lanes
    }

    // ---- readout: 2-qubit circuit (R1/R2-verified structure), libm trig ----
    const float sh0 = sinf(0.5f * h0), ch0 = cosf(0.5f * h0);
    const float sh1 = sinf(0.5f * h1), ch1 = cosf(0.5f * h1);
    float vr0 = ch0 * ch1, vr1 = ch0 * sh1, vr2 = sh0 * ch1, vr3 = sh0 * sh1;
    float vi0 = 0.f, vi1 = 0.f, vi2 = 0.f, vi3 = 0.f;

    #pragma unroll
    for (int li = 0; li < 2; ++li) {
        #pragma unroll
        for (int w = 0; w < 2; ++w) {
            const float phi = w_out[li * 6 + w * 3 + 0];
            const float the = w_out[li * 6 + w * 3 + 1];
            const float ome = w_out[li * 6 + w * 3 + 2];
            const float cs = cosf(0.5f * the), ss = sinf(0.5f * the);
            const float cp = cosf(0.5f * (phi + ome)), sp = sinf(0.5f * (phi + ome));
            const float cm = cosf(0.5f * (phi - ome)), sm = sinf(0.5f * (phi - ome));
            const float are = cp * cs, aim = -sp * cs;
            const float bre = cm * ss, bim = sm * ss;
            #define AP2(r0, i0, r1, i1) do {                                  \
                float n0r = are*(r0) - aim*(i0) - bre*(r1) + bim*(i1);        \
                float n0i = are*(i0) + aim*(r0) - bre*(i1) - bim*(r1);        \
                float n1r = bre*(r0) + bim*(i0) + are*(r1) + aim*(i1);        \
                float n1i = bre*(i0) - bim*(r0) + are*(i1) - aim*(r1);        \
                r0 = n0r; i0 = n0i; r1 = n1r; i1 = n1i; } while (0)
            if (w == 0) { AP2(vr0, vi0, vr2, vi2); AP2(vr1, vi1, vr3, vi3); }
            else        { AP2(vr0, vi0, vr1, vi1); AP2(vr2, vi2, vr3, vi3); }
            #undef AP2
        }
        // CNOT(0,1) then CNOT(1,0): composed perm [0,2,3,1]
        float tr1 = vr2, ti1 = vi2, tr2 = vr3, ti2 = vi3, tr3 = vr1, ti3 = vi1;
        vr1 = tr1; vi1 = ti1; vr2 = tr2; vi2 = ti2; vr3 = tr3; vi3 = ti3;
    }

    const float outv = (vr0 * vr0 + vi0 * vi0 + vr1 * vr1 + vi1 * vi1) -
                       (vr2 * vr2 + vi2 * vi2 + vr3 * vr3 + vi3 * vi3);
    if (lam == 0) out[b] = outv;
}

extern "C" void kernel_launch(void* const* d_in, const int* in_sizes, int n_in,
                              void* d_out, int out_size, void* d_ws, size_t ws_size,
                              hipStream_t stream) {
    const float* x_seq = (const float*)d_in[0];
    const float* w_rec = (const float*)d_in[1];
    const float* w_out = (const float*)d_in[2];
    float* out = (float*)d_out;

    const int B = out_size;                 // 8192
    const int T = in_sizes[0] / (B * 3);    // 32

    const long long threads = (long long)B * 16;
    const int block = 256;
    const int grid = (int)((threads + block - 1) / block);
    hipLaunchKernelGGL(qrnn_kernel, dim3(grid), dim3(block), 0, stream,
                       x_seq, w_rec, w_out, out, T, B);
}

// Round 5
// 85.425 us; speedup vs baseline: 1.5128x; 1.0467x over previous
//
#include <hip/hip_runtime.h>
#include <math.h>

// ---------------------------------------------------------------------------
// FullyQuantumRNN, round 5: 16 lanes/batch x 2 amps/lane, packed-f32 state.
// vs R4: (1) x_seq staged to LDS once per block (8KB), per-step broadcast
// ds_read_b128 prefetched 1 step ahead -- zero global loads in the recurrence;
// (2) float2-packed gates/diagonals (v_pk_fma_f32 class); (3) lane relabel
// A(8,4,2,1)=(1,2,7,15) puts 7/9 hot xor-masks on single-DPP; (4) next-step
// x-trig computed off the recurrence chain. Algebra identical to R4 (verified
// absmax 2.4e-7); all masks constexpr-derived + static_asserted.
// ---------------------------------------------------------------------------

typedef __attribute__((ext_vector_type(2))) float f2;

// ---- compile-time permutation algebra (R1/R2/R4-verified) ----
constexpr int cnot_ct(int idx, int c, int t) {
    return (idx & (1 << (4 - c))) ? (idx ^ (1 << (4 - t))) : idx;
}
constexpr int Pfwd_ct(int x, int r) {            // layer perm: new[i]=old[P(i)]
    for (int w = 4; w >= 0; --w) x = cnot_ct(x, w, (w + r) % 5);
    return x;
}
constexpr int Pinv_ct(int x, int r) {
    for (int w = 0; w <= 4; ++w) x = cnot_ct(x, w, (w + r) % 5);
    return x;
}
static_assert(Pinv_ct(Pfwd_ct(13, 1), 1) == 13, "inv1");
static_assert(Pinv_ct(Pfwd_ct(22, 2), 2) == 22, "inv2");

constexpr int GMASK[10] = {16, 8, 4, 2, 1,
                           Pfwd_ct(16,1), Pfwd_ct(8,1), Pfwd_ct(4,1), Pfwd_ct(2,1), Pfwd_ct(1,1)};
constexpr int fmask_l1(int pb) {
    int f = 0;
    for (int b = 0; b < 5; ++b) if ((Pinv_ct(1 << b, 1) >> pb) & 1) f |= 1 << b;
    return f;
}
constexpr int FMASK[10] = {16, 8, 4, 2, 1,
                           fmask_l1(4), fmask_l1(3), fmask_l1(2), fmask_l1(1), fmask_l1(0)};
constexpr int cinv_ct(int x) { return Pinv_ct(Pinv_ct(x, 1), 2); }
constexpr int fmask_fin(int pb) {
    int f = 0;
    for (int b = 0; b < 5; ++b) if ((cinv_ct(1 << b) >> pb) & 1) f |= 1 << b;
    return f;
}
constexpr int SF3 = fmask_fin(1);
constexpr int SF4 = fmask_fin(0);
constexpr int FMf(int b) { return Pfwd_ct(Pfwd_ct(1 << b, 2), 1); }

constexpr unsigned span3_ct(int a, int b, int c) {
    unsigned m = 0;
    for (int i = 0; i < 8; ++i) {
        int v = ((i & 1) ? a : 0) ^ ((i & 2) ? b : 0) ^ ((i & 4) ? c : 0);
        m |= 1u << v;
    }
    return m;
}
constexpr unsigned PSPAN = span3_ct(FMf(4), FMf(3), FMf(2));
static_assert(PSPAN == span3_ct(16, 1, 14), "p-stage basis {16,1,14} spans PSPAN");
static_assert((PSPAN >> 16) & 1, "16 in PSPAN: reg dim collapsed by p-reduce");
constexpr bool in_pspan(int v) { return (PSPAN >> (v & 31)) & 1; }
constexpr bool pspan_ok() {
    for (int v = 0; v < 32; ++v) if ((PSPAN >> v) & 1) {
        if (__builtin_popcount(v & SF3) & 1) return false;
        if (__builtin_popcount(v & SF4) & 1) return false;
    }
    return true;
}
static_assert(pspan_ok(), "sign functionals vanish on PSPAN");
static_assert((SF3 & 16) == 0 && (SF4 & 16) == 0, "signs lane-only");

// q-stage coset reps (mod PSPAN) -- R4-verified conditions
constexpr int QM1 = 12;
constexpr int QM0 = 8;
static_assert((QM1 & 16) == 0 && (QM0 & 16) == 0, "q reps lane-only");
static_assert(in_pspan(QM1 ^ FMf(1)), "QM1 ~ FMf(1) mod PSPAN");
static_assert(in_pspan(QM0 ^ FMf(0)), "QM0 ~ FMf(0) mod PSPAN");
static_assert(!in_pspan(QM1) && !in_pspan(QM0) && !in_pspan(QM1 ^ QM0),
              "q reps independent mod duplication subgroup");

// ---- lane relabel A: A(1)=15, A(2)=7, A(4)=2, A(8)=1 (7/9 hot masks 1-DPP) --
constexpr int A4(int l) {
    return ((l & 1) ? 15 : 0) ^ ((l & 2) ? 7 : 0) ^ ((l & 4) ? 2 : 0) ^ ((l & 8) ? 1 : 0);
}
constexpr int Ainv4(int p) {
    for (int l = 0; l < 16; ++l) if (A4(l) == p) return l;
    return -1;
}
constexpr bool a_bij() {
    for (int p = 0; p < 16; ++p) { int l = Ainv4(p); if (l < 0 || A4(l) != p) return false; }
    for (int p = 0; p < 16; ++p) {
        int lin = ((p&1)?Ainv4(1):0) ^ ((p&2)?Ainv4(2):0) ^ ((p&4)?Ainv4(4):0) ^ ((p&8)?Ainv4(8):0);
        if (lin != Ainv4(p)) return false;
    }
    return true;
}
static_assert(a_bij(), "A bijective, inverse linear");

__device__ __forceinline__ int ainv_rt(int p) {
    return ((p & 1) ? Ainv4(1) : 0) ^ ((p & 2) ? Ainv4(2) : 0) ^
           ((p & 4) ? Ainv4(4) : 0) ^ ((p & 8) ? Ainv4(8) : 0);
}

__device__ __forceinline__ int pinv_rt(int x, int r) {
    #pragma unroll
    for (int w = 0; w < 5; ++w) {
        int cbit = 1 << (4 - w), tbit = 1 << (4 - ((w + r) % 5));
        if (x & cbit) x ^= tbit;
    }
    return x;
}

// ---- cross-lane xor move: pure DPP (composed when needed), zero-LDS path ----
template<int CTRL> __device__ __forceinline__ float dppf(float x) {
    return __int_as_float(__builtin_amdgcn_mov_dpp(__float_as_int(x), CTRL, 0xF, 0xF, true));
}
template<int PL> __device__ __forceinline__ float mvf(float x) {
    if constexpr (PL == 0)  return x;
    else if constexpr (PL == 1)  return dppf<0xB1>(x);    // quad_perm xor1
    else if constexpr (PL == 2)  return dppf<0x4E>(x);    // quad_perm xor2
    else if constexpr (PL == 3)  return dppf<0x1B>(x);    // quad_perm xor3
    else if constexpr (PL == 7)  return dppf<0x141>(x);   // row_half_mirror = xor7
    else if constexpr (PL == 15) return dppf<0x140>(x);   // row_mirror = xor15
    else if constexpr (PL & 8)   return mvf<PL ^ 15>(dppf<0x140>(x));
    else                         return mvf<PL ^ 7>(dppf<0x141>(x));
}

// ---- one Ry gate, packed: VR = C2*VR + S2*PR ; VI = C2*VI + S2*PI ----
template<int g>
__device__ __forceinline__ void ry_gate(f2& VR, f2& VI,
                                        const f2 (&C2)[10], const f2 (&S2)[10]) {
    constexpr int m  = GMASK[g];
    constexpr int rm = (m >> 4) & 1;          // slot xor
    constexpr int pl = A4(m & 15);            // physical lane xor
    f2 PR, PI;
    if constexpr (rm == 0) {
        PR.x = mvf<pl>(VR.x); PR.y = mvf<pl>(VR.y);
        PI.x = mvf<pl>(VI.x); PI.y = mvf<pl>(VI.y);
    } else {
        PR.x = mvf<pl>(VR.y); PR.y = mvf<pl>(VR.x);
        PI.x = mvf<pl>(VI.y); PI.y = mvf<pl>(VI.x);
    }
    VR = C2[g] * VR + S2[g] * PR;
    VI = C2[g] * VI + S2[g] * PI;
}

__global__ __launch_bounds__(256, 2) void qrnn_kernel(
    const float* __restrict__ x_seq, const float* __restrict__ w_rec,
    const float* __restrict__ w_out, float* __restrict__ out, int T, int B) {

    __shared__ float4 xs4[16 * 32];           // [local-batch][step] = {x0,x1,x2,-}

    const int tloc = threadIdx.x;
    const int lb   = tloc >> 4;               // local batch 0..15
    const int lam  = tloc & 15;               // physical lane part
    const int b0   = blockIdx.x * 16;
    const int b    = b0 + lb;

    // ---- stage all x for this block's 16 batches into LDS (once) ----
    #pragma unroll
    for (int q = 0; q < 2; ++q) {
        const int p  = tloc + q * 256;        // 0..511 = (t,lb') pairs
        const int ts = p >> 4, lbs = p & 15;
        const int g  = (ts * B + (b0 + lbs)) * 3;
        float4 v;
        v.x = x_seq[g]; v.y = x_seq[g + 1]; v.z = x_seq[g + 2]; v.w = 0.f;
        xs4[lbs * 32 + ts] = v;
    }
    __syncthreads();

    const int l = ainv_rt(lam);               // logical amp bits 3..0 (wires 1..4)

    // ---- prologue (libm precision -- coefficient error amplifies over T) ----
    f2 C2[10], S2[10];
    #pragma unroll
    for (int g = 0; g < 10; ++g) {
        const float the = w_rec[(g / 5) * 15 + (g % 5) * 3 + 1];
        const float c = cosf(0.5f * the), s = sinf(0.5f * the);
        const bool bl = __popc(l & (FMASK[g] & 15)) & 1;    // lane part of beta
        const bool fb = (FMASK[g] >> 4) & 1;                // slot part
        const float sg = bl ? s : -s;
        C2[g].x = c;  C2[g].y = c;
        S2[g].x = sg; S2[g].y = fb ? -sg : sg;
    }
    f2 P0r2, P0i2, E1r2, E1i2;
    #pragma unroll
    for (int r = 0; r < 2; ++r) {
        const int s_idx = (r << 4) | l;         // storage index (layer-0 frame)
        const int j     = pinv_rt(s_idx, 1);    // layer-1 frame index
        float a0 = 0.f, e1 = 0.f;
        #pragma unroll
        for (int w = 0; w < 5; ++w) {
            const float sg0 = ((s_idx >> (4 - w)) & 1) ? 0.5f : -0.5f;
            const float sg1 = ((j     >> (4 - w)) & 1) ? 0.5f : -0.5f;
            a0 += sg0 * w_rec[w * 3 + 0];              // phi, layer 0
            e1 += sg0 * w_rec[w * 3 + 2];              // omega, layer 0
            e1 += sg1 * w_rec[15 + w * 3 + 0];         // phi, layer 1
        }
        if (r == 0) { P0r2.x = cosf(a0); P0i2.x = sinf(a0);
                      E1r2.x = cosf(e1); E1i2.x = sinf(e1); }
        else        { P0r2.y = cosf(a0); P0i2.y = sinf(a0);
                      E1r2.y = cosf(e1); E1i2.y = sinf(e1); }
    }
    const float s3f = (__popc(l & SF3) & 1) ? -1.f : 1.f;
    const float s4f = (__popc(l & SF4) & 1) ? -1.f : 1.f;
    const float o1 = (l & 8) ? 0.25f : 0.f;   // wire1 (x1)
    const float o2 = (l & 4) ? 0.25f : 0.f;   // wire2 (x2)
    const float o3 = (l & 2) ? 0.25f : 0.f;   // wire3 (h0)
    const float o4 = (l & 1) ? 0.25f : 0.f;   // wire4 (h1)
    constexpr float K = 0.5f * 0.15915494309189535f;   // 0.5/(2*pi)

    // trig of step 0's x (loop-carried; next step's computed off-chain)
    const float4* xrow = &xs4[lb * 32];
    float4 cx = xrow[0];
    float c0 = __builtin_amdgcn_cosf(cx.x * K);
    float s0 = __builtin_amdgcn_cosf(fmaf(cx.x, K, -0.25f));
    float f1 = __builtin_amdgcn_cosf(fmaf(cx.y, K, -o1));
    float f2v = __builtin_amdgcn_cosf(fmaf(cx.z, K, -o2));
    float h0 = 0.f, h1 = 0.f;

    #pragma unroll 1
    for (int t = 0; t < T; ++t) {
        const int tn = (t + 1 < T) ? t + 1 : t;
        const float4 nx = xrow[tn];           // LDS prefetch for next step

        // recurrence-top chain: only h -> 2 v_cos -> product
        const float f3 = __builtin_amdgcn_cosf(fmaf(h0, K, -o3));
        const float f4 = __builtin_amdgcn_cosf(fmaf(h1, K, -o4));
        const float Xl = (f1 * f2v) * (f3 * f4);
        f2 bp; bp.x = c0 * Xl; bp.y = s0 * Xl;
        f2 VR = bp * P0r2;                    // D_phi0 folded into init
        f2 VI = bp * P0i2;

        ry_gate<0>(VR, VI, C2, S2); ry_gate<1>(VR, VI, C2, S2);
        ry_gate<2>(VR, VI, C2, S2); ry_gate<3>(VR, VI, C2, S2);
        ry_gate<4>(VR, VI, C2, S2);
        {   // merged diagonal E1 = D_omega0 * (P1-frame D_phi1)
            const f2 nr = VR * E1r2 - VI * E1i2;
            const f2 ni = VR * E1i2 + VI * E1r2;
            VR = nr; VI = ni;
        }
        ry_gate<5>(VR, VI, C2, S2); ry_gate<6>(VR, VI, C2, S2);
        ry_gate<7>(VR, VI, C2, S2); ry_gate<8>(VR, VI, C2, S2);
        ry_gate<9>(VR, VI, C2, S2);           // D_omega1 dropped (phase-blind)

        // expZ reduce: p-stages over span{16,1,14}, then signed q-stages
        const f2 P = VR * VR + VI * VI;
        float tq = P.x + P.y;                 // mask16 (slot)
        tq += mvf<A4(1)>(tq);                 // mask1  -> phys 15 (row_mirror)
        tq += mvf<A4(14)>(tq);                // mask14 -> phys 4  (composed)
        float q0 = s3f * tq, q1 = s4f * tq;
        q0 += mvf<A4(QM1)>(q0);               // QM1=12 -> phys 3 (quad_perm)
        q1 += mvf<A4(QM1)>(q1);
        q0 += mvf<A4(QM0)>(q0);               // QM0=8  -> phys 1 (quad_perm)
        q1 += mvf<A4(QM0)>(q1);
        h0 = q0; h1 = q1;                     // uniform across all 16 lanes

        // next step's x-trig, off the recurrence chain
        c0  = __builtin_amdgcn_cosf(nx.x * K);
        s0  = __builtin_amdgcn_cosf(fmaf(nx.x, K, -0.25f));
        f1  = __builtin_amdgcn_cosf(fmaf(nx.y, K, -o1));
        f2v = __builtin_amdgcn_cosf(fmaf(nx.z, K, -o2));
    }

    // ---- readout: 2-qubit circuit (R1-verified structure), libm trig ----
    const float sh0 = sinf(0.5f * h0), ch0 = cosf(0.5f * h0);
    const float sh1 = sinf(0.5f * h1), ch1 = cosf(0.5f * h1);
    float vr0 = ch0 * ch1, vr1 = ch0 * sh1, vr2 = sh0 * ch1, vr3 = sh0 * sh1;
    float vi0 = 0.f, vi1 = 0.f, vi2 = 0.f, vi3 = 0.f;

    #pragma unroll
    for (int li = 0; li < 2; ++li) {
        #pragma unroll
        for (int w = 0; w < 2; ++w) {
            const float phi = w_out[li * 6 + w * 3 + 0];
            const float the = w_out[li * 6 + w * 3 + 1];
            const float ome = w_out[li * 6 + w * 3 + 2];
            const float cs = cosf(0.5f * the), ss = sinf(0.5f * the);
            const float cp = cosf(0.5f * (phi + ome)), sp = sinf(0.5f * (phi + ome));
            const float cm = cosf(0.5f * (phi - ome)), sm = sinf(0.5f * (phi - ome));
            const float are = cp * cs, aim = -sp * cs;
            const float bre = cm * ss, bim = sm * ss;
            #define AP2(r0, i0, r1, i1) do {                                  \
                float n0r = are*(r0) - aim*(i0) - bre*(r1) + bim*(i1);        \
                float n0i = are*(i0) + aim*(r0) - bre*(i1) - bim*(r1);        \
                float n1r = bre*(r0) + bim*(i0) + are*(r1) + aim*(i1);        \
                float n1i = bre*(i0) - bim*(r0) + are*(i1) - aim*(r1);        \
                r0 = n0r; i0 = n0i; r1 = n1r; i1 = n1i; } while (0)
            if (w == 0) { AP2(vr0, vi0, vr2, vi2); AP2(vr1, vi1, vr3, vi3); }
            else        { AP2(vr0, vi0, vr1, vi1); AP2(vr2, vi2, vr3, vi3); }
            #undef AP2
        }
        // CNOT(0,1) then CNOT(1,0): composed perm [0,2,3,1]
        float tr1 = vr2, ti1 = vi2, tr2 = vr3, ti2 = vi3, tr3 = vr1, ti3 = vi1;
        vr1 = tr1; vi1 = ti1; vr2 = tr2; vi2 = ti2; vr3 = tr3; vi3 = ti3;
    }

    const float outv = (vr0 * vr0 + vi0 * vi0 + vr1 * vr1 + vi1 * vi1) -
                       (vr2 * vr2 + vi2 * vi2 + vr3 * vr3 + vi3 * vi3);
    if (lam == 0) out[b] = outv;
}

extern "C" void kernel_launch(void* const* d_in, const int* in_sizes, int n_in,
                              void* d_out, int out_size, void* d_ws, size_t ws_size,
                              hipStream_t stream) {
    const float* x_seq = (const float*)d_in[0];
    const float* w_rec = (const float*)d_in[1];
    const float* w_out = (const float*)d_in[2];
    float* out = (float*)d_out;

    const int B = out_size;                 // 8192
    const int T = in_sizes[0] / (B * 3);    // 32

    const int grid = (B * 16) / 256;        // exact: 16 lanes/batch, 16 batches/block
    hipLaunchKernelGGL(qrnn_kernel, dim3(grid), dim3(256), 0, stream,
                       x_seq, w_rec, w_out, out, T, B);
}